// Round 2
// baseline (314.292 us; speedup 1.0000x reference)
//
#include <hip/hip_runtime.h>

// WideAndDeep fused inference, fp32. Round 2: no LDS weight staging.
// Weights are read directly from global (L2/L3-resident; identical addresses
// across all blocks). Only 4 barriers per block (gather + 3 layer boundaries).
// LDS: xs[32][128] (16KB, reused as h2) + h1[32][256] (32KB, reused as h3) = 48KB.

#define NT 512
#define TS 32

constexpr int NUM_USERS = 500000;
// 1/sqrt(1 + 1e-5): eval-mode BN with running_mean=0, running_var=1
constexpr float BN_INV = 0.9999950000374997f;

struct __align__(16) Smem {
    float xs[TS * 128];   // input x; later reused as h2 (32x128)
    float h1[TS * 256];   // h1; later reused as h3 (32x64)
};

#define FMA4(xk, wv, a)                      \
    do {                                     \
        (a).x = fmaf((xk), (wv).x, (a).x);   \
        (a).y = fmaf((xk), (wv).y, (a).y);   \
        (a).z = fmaf((xk), (wv).z, (a).z);   \
        (a).w = fmaf((xk), (wv).w, (a).w);   \
    } while (0)

// One Linear(K,N) + ReLU + eval-BN layer over a 32-sample tile in LDS.
// Thread t computes S=N/64 samples x 4 features. Weight rows straight from
// global memory (L2-hit after first block); xv reads are wave-broadcast LDS.
template <int K, int N>
__device__ __forceinline__ void mlp_layer(
    const float* __restrict__ w, const float* __restrict__ bias,
    const float* __restrict__ gamma, const float* __restrict__ beta,
    const float* in_lds, float* out_lds, int t)
{
    constexpr int JG = N / 4;   // feature groups of 4
    constexpr int S  = N / 64;  // samples per thread (TS*JG/NT)
    constexpr int NW = N / 4;   // weight row stride in float4

    const int j0 = (t % JG) * 4;
    const int s0 = (t / JG) * S;

    float4 acc[S];
#pragma unroll
    for (int s = 0; s < S; ++s) acc[s] = make_float4(0.f, 0.f, 0.f, 0.f);

    const float4* wp = (const float4*)w + (j0 >> 2);

#pragma unroll 4
    for (int k4 = 0; k4 < K; k4 += 4) {
        // 4 weight rows for this thread's 4 features: 16B global loads,
        // coalesced across the wave, L2/L1-resident after first touch.
        float4 wv0 = wp[(k4 + 0) * NW];
        float4 wv1 = wp[(k4 + 1) * NW];
        float4 wv2 = wp[(k4 + 2) * NW];
        float4 wv3 = wp[(k4 + 3) * NW];
        float4 xv[S];
#pragma unroll
        for (int s = 0; s < S; ++s)
            xv[s] = *(const float4*)&in_lds[(s0 + s) * K + k4];
#pragma unroll
        for (int s = 0; s < S; ++s) {
            FMA4(xv[s].x, wv0, acc[s]);
            FMA4(xv[s].y, wv1, acc[s]);
            FMA4(xv[s].z, wv2, acc[s]);
            FMA4(xv[s].w, wv3, acc[s]);
        }
    }

    // epilogue: bias -> relu -> BN(eval), write to out LDS
    const float4 bv = *(const float4*)&bias[j0];
    const float4 gv = *(const float4*)&gamma[j0];
    const float4 ev = *(const float4*)&beta[j0];
#pragma unroll
    for (int s = 0; s < S; ++s) {
        float4 o;
        o.x = fmaxf(acc[s].x + bv.x, 0.f) * (gv.x * BN_INV) + ev.x;
        o.y = fmaxf(acc[s].y + bv.y, 0.f) * (gv.y * BN_INV) + ev.y;
        o.z = fmaxf(acc[s].z + bv.z, 0.f) * (gv.z * BN_INV) + ev.z;
        o.w = fmaxf(acc[s].w + bv.w, 0.f) * (gv.w * BN_INV) + ev.w;
        *(float4*)&out_lds[(s0 + s) * N + j0] = o;
    }
}

__global__ __launch_bounds__(NT, 4) void wd_kernel(
    const int* __restrict__ user_ids, const int* __restrict__ item_ids,
    const float* __restrict__ wide_w, const float* __restrict__ wide_b,
    const float* __restrict__ user_table, const float* __restrict__ item_table,
    const float* __restrict__ w1, const float* __restrict__ b1,
    const float* __restrict__ g1, const float* __restrict__ be1,
    const float* __restrict__ w2, const float* __restrict__ b2,
    const float* __restrict__ g2, const float* __restrict__ be2,
    const float* __restrict__ w3, const float* __restrict__ b3,
    const float* __restrict__ g3, const float* __restrict__ be3,
    const float* __restrict__ w4, const float* __restrict__ b4,
    float* __restrict__ out)
{
    __shared__ Smem sm;
    const int t = threadIdx.x;
    const int sbase = blockIdx.x * TS;

    // ---- gather: xs[s][0:64] = user row, xs[s][64:128] = item row ----
    {
        const int s = t >> 4;         // 0..31
        const int p = t & 15;         // 0..15  (16 float4 per 64-float half)
        const int uid = user_ids[sbase + s];
        const int iid = item_ids[sbase + s];
        ((float4*)&sm.xs[s * 128])[p] =
            ((const float4*)(user_table + (long)uid * 64))[p];
        ((float4*)&sm.xs[s * 128])[16 + p] =
            ((const float4*)(item_table + (long)iid * 64))[p];
    }

    // ---- wide path: computed by the thread that will write out[s] ----
    float widev = 0.0f;
    if (t < TS * 8 && (t & 7) == 0) {
        const int s = t >> 3;
        const int uid = user_ids[sbase + s];
        const int iid = item_ids[sbase + s];
        widev = wide_w[uid] + wide_w[NUM_USERS + iid] + wide_b[0];
    }
    __syncthreads();  // gather complete

    // ---- deep MLP ----
    mlp_layer<128, 256>(w1, b1, g1, be1, sm.xs, sm.h1, t);  // x  -> h1
    __syncthreads();
    mlp_layer<256, 128>(w2, b2, g2, be2, sm.h1, sm.xs, t);  // h1 -> h2 (in xs)
    __syncthreads();
    mlp_layer<128, 64 >(w3, b3, g3, be3, sm.xs, sm.h1, t);  // h2 -> h3 (in h1)
    __syncthreads();

    // ---- layer 4: dot(h3[s], w4) + b4, 8 threads per sample ----
    if (t < TS * 8) {
        const int s = t >> 3;
        const int g = t & 7;
        const float* h = &sm.h1[s * 64 + g * 8];
        const float4 ha = *(const float4*)(h);
        const float4 hb = *(const float4*)(h + 4);
        const float4 wa = *(const float4*)(w4 + g * 8);
        const float4 wb = *(const float4*)(w4 + g * 8 + 4);
        float p = ha.x * wa.x + ha.y * wa.y + ha.z * wa.z + ha.w * wa.w
                + hb.x * wb.x + hb.y * wb.y + hb.z * wb.z + hb.w * wb.w;
        p += __shfl_down(p, 4);
        p += __shfl_down(p, 2);
        p += __shfl_down(p, 1);
        if (g == 0) out[sbase + s] = widev + p + b4[0];
    }
}

extern "C" void kernel_launch(void* const* d_in, const int* in_sizes, int n_in,
                              void* d_out, int out_size, void* d_ws, size_t ws_size,
                              hipStream_t stream) {
    (void)in_sizes; (void)n_in; (void)d_ws; (void)ws_size;
    const int*   user_ids   = (const int*)d_in[0];
    const int*   item_ids   = (const int*)d_in[1];
    const float* wide_w     = (const float*)d_in[2];
    const float* wide_b     = (const float*)d_in[3];
    const float* user_table = (const float*)d_in[4];
    const float* item_table = (const float*)d_in[5];
    const float* w1 = (const float*)d_in[6];
    const float* b1 = (const float*)d_in[7];
    const float* g1 = (const float*)d_in[8];
    const float* be1 = (const float*)d_in[9];
    const float* w2 = (const float*)d_in[10];
    const float* b2 = (const float*)d_in[11];
    const float* g2 = (const float*)d_in[12];
    const float* be2 = (const float*)d_in[13];
    const float* w3 = (const float*)d_in[14];
    const float* b3 = (const float*)d_in[15];
    const float* g3 = (const float*)d_in[16];
    const float* be3 = (const float*)d_in[17];
    const float* w4 = (const float*)d_in[18];
    const float* b4 = (const float*)d_in[19];
    float* out = (float*)d_out;

    const int grid = 16384 / TS;  // 512 blocks
    wd_kernel<<<grid, NT, 0, stream>>>(
        user_ids, item_ids, wide_w, wide_b, user_table, item_table,
        w1, b1, g1, be1, w2, b2, g2, be2, w3, b3, g3, be3, w4, b4, out);
}

// Round 3
// 310.895 us; speedup vs baseline: 1.0109x; 1.0109x over previous
//
#include <hip/hip_runtime.h>

// WideAndDeep fused inference, fp32. Round 3: big sample-tiles per wave.
// Each wave computes [SM samples x FS features] (L1:16x64, L2:16x32, L3:8x32),
// cutting per-wave weight streaming 4-8x vs round 2 (320 MB total L2 traffic)
// and giving 64-128 FMA-instrs per 8 loads -> latency hideable at 4 waves/SIMD.
// Activation LDS strides padded (132/260/68) to break stride-128 bank conflicts.

#define NT 512
#define TS 32

constexpr int NUM_USERS = 500000;
// 1/sqrt(1 + 1e-5): eval-mode BN with running_mean=0, running_var=1
constexpr float BN_INV = 0.9999950000374997f;

struct __align__(16) Smem {
    float xs[TS * 132];   // input x (stride 132); reused as h2 (stride 132)
    float h1[TS * 260];   // h1 (stride 260); reused as h3 (stride 68)
};

#define FMA4(xk, wv, a)                      \
    do {                                     \
        (a).x = fmaf((xk), (wv).x, (a).x);   \
        (a).y = fmaf((xk), (wv).y, (a).y);   \
        (a).z = fmaf((xk), (wv).z, (a).z);   \
        (a).w = fmaf((xk), (wv).w, (a).w);   \
    } while (0)

// Linear(K,N)+ReLU+BN(eval) over the 32-sample tile.
// KS/NS = padded LDS strides. FS = features per wave-slice.
// Lane layout: jg = lane%JG (4 features each), sg = lane/JG (SPL samples each).
template <int K, int KS, int N, int NS, int FS>
__device__ __forceinline__ void mlp_layer(
    const float* __restrict__ w, const float* __restrict__ bias,
    const float* __restrict__ gamma, const float* __restrict__ beta,
    const float* in_lds, float* out_lds, int t)
{
    constexpr int JG     = FS / 4;            // feature groups per wave
    constexpr int SG     = 64 / JG;           // sample groups per wave
    constexpr int NSLICE = N / FS;            // feature slices (waves across N)
    constexpr int SM     = TS * NSLICE / 8;   // samples per wave tile (8 waves)
    constexpr int SPL    = SM / SG;           // samples per lane
    constexpr int NW4    = N / 4;             // weight row stride in float4
    static_assert(SPL * SG == SM, "layout");

    const int wave = t >> 6, lane = t & 63;
    const int wslice = wave % NSLICE, wsamp = wave / NSLICE;
    const int jg = lane % JG, sg = lane / JG;
    const int j0 = wslice * FS + jg * 4;
    const int s0 = wsamp * SM + sg * SPL;

    float4 acc[SPL];
#pragma unroll
    for (int s = 0; s < SPL; ++s) acc[s] = make_float4(0.f, 0.f, 0.f, 0.f);

    const float4* wp = (const float4*)w + (j0 >> 2);

#pragma unroll 4
    for (int k4 = 0; k4 < K; k4 += 4) {
        // 4 weight rows x float4: 256B coalesced segment per instr, L2-hot.
        float4 wv0 = wp[(k4 + 0) * NW4];
        float4 wv1 = wp[(k4 + 1) * NW4];
        float4 wv2 = wp[(k4 + 2) * NW4];
        float4 wv3 = wp[(k4 + 3) * NW4];
        float4 xv[SPL];
#pragma unroll
        for (int s = 0; s < SPL; ++s)
            xv[s] = *(const float4*)&in_lds[(s0 + s) * KS + k4];
#pragma unroll
        for (int s = 0; s < SPL; ++s) {
            FMA4(xv[s].x, wv0, acc[s]);
            FMA4(xv[s].y, wv1, acc[s]);
            FMA4(xv[s].z, wv2, acc[s]);
            FMA4(xv[s].w, wv3, acc[s]);
        }
    }

    const float4 bv = *(const float4*)&bias[j0];
    const float4 gv = *(const float4*)&gamma[j0];
    const float4 ev = *(const float4*)&beta[j0];
#pragma unroll
    for (int s = 0; s < SPL; ++s) {
        float4 o;
        o.x = fmaxf(acc[s].x + bv.x, 0.f) * (gv.x * BN_INV) + ev.x;
        o.y = fmaxf(acc[s].y + bv.y, 0.f) * (gv.y * BN_INV) + ev.y;
        o.z = fmaxf(acc[s].z + bv.z, 0.f) * (gv.z * BN_INV) + ev.z;
        o.w = fmaxf(acc[s].w + bv.w, 0.f) * (gv.w * BN_INV) + ev.w;
        *(float4*)&out_lds[(s0 + s) * NS + j0] = o;
    }
}

__global__ __launch_bounds__(NT, 4) void wd_kernel(
    const int* __restrict__ user_ids, const int* __restrict__ item_ids,
    const float* __restrict__ wide_w, const float* __restrict__ wide_b,
    const float* __restrict__ user_table, const float* __restrict__ item_table,
    const float* __restrict__ w1, const float* __restrict__ b1,
    const float* __restrict__ g1, const float* __restrict__ be1,
    const float* __restrict__ w2, const float* __restrict__ b2,
    const float* __restrict__ g2, const float* __restrict__ be2,
    const float* __restrict__ w3, const float* __restrict__ b3,
    const float* __restrict__ g3, const float* __restrict__ be3,
    const float* __restrict__ w4, const float* __restrict__ b4,
    float* __restrict__ out)
{
    __shared__ Smem sm;
    const int t = threadIdx.x;
    const int sbase = blockIdx.x * TS;

    // ---- gather: xs[s][0:64] = user row, xs[s][64:128] = item row ----
    {
        const int s = t >> 4;         // 0..31
        const int p = t & 15;         // 0..15
        const int uid = user_ids[sbase + s];
        const int iid = item_ids[sbase + s];
        float4* row = (float4*)&sm.xs[s * 132];
        row[p]      = ((const float4*)(user_table + (long)uid * 64))[p];
        row[16 + p] = ((const float4*)(item_table + (long)iid * 64))[p];
    }

    // ---- wide path ----
    float widev = 0.0f;
    if (t < TS * 8 && (t & 7) == 0) {
        const int s = t >> 3;
        const int uid = user_ids[sbase + s];
        const int iid = item_ids[sbase + s];
        widev = wide_w[uid] + wide_w[NUM_USERS + iid] + wide_b[0];
    }
    __syncthreads();  // gather complete

    // ---- deep MLP ----
    mlp_layer<128, 132, 256, 260, 64>(w1, b1, g1, be1, sm.xs, sm.h1, t);
    __syncthreads();
    mlp_layer<256, 260, 128, 132, 32>(w2, b2, g2, be2, sm.h1, sm.xs, t);
    __syncthreads();
    mlp_layer<128, 132,  64,  68, 32>(w3, b3, g3, be3, sm.xs, sm.h1, t);
    __syncthreads();

    // ---- layer 4: dot(h3[s], w4) + b4, 8 threads per sample ----
    if (t < TS * 8) {
        const int s = t >> 3;
        const int g = t & 7;
        const float* h = &sm.h1[s * 68 + g * 8];
        const float4 ha = *(const float4*)(h);
        const float4 hb = *(const float4*)(h + 4);
        const float4 wa = *(const float4*)(w4 + g * 8);
        const float4 wb = *(const float4*)(w4 + g * 8 + 4);
        float p = ha.x * wa.x + ha.y * wa.y + ha.z * wa.z + ha.w * wa.w
                + hb.x * wb.x + hb.y * wb.y + hb.z * wb.z + hb.w * wb.w;
        p += __shfl_down(p, 4);
        p += __shfl_down(p, 2);
        p += __shfl_down(p, 1);
        if (g == 0) out[sbase + s] = widev + p + b4[0];
    }
}

extern "C" void kernel_launch(void* const* d_in, const int* in_sizes, int n_in,
                              void* d_out, int out_size, void* d_ws, size_t ws_size,
                              hipStream_t stream) {
    (void)in_sizes; (void)n_in; (void)d_ws; (void)ws_size;
    const int*   user_ids   = (const int*)d_in[0];
    const int*   item_ids   = (const int*)d_in[1];
    const float* wide_w     = (const float*)d_in[2];
    const float* wide_b     = (const float*)d_in[3];
    const float* user_table = (const float*)d_in[4];
    const float* item_table = (const float*)d_in[5];
    const float* w1 = (const float*)d_in[6];
    const float* b1 = (const float*)d_in[7];
    const float* g1 = (const float*)d_in[8];
    const float* be1 = (const float*)d_in[9];
    const float* w2 = (const float*)d_in[10];
    const float* b2 = (const float*)d_in[11];
    const float* g2 = (const float*)d_in[12];
    const float* be2 = (const float*)d_in[13];
    const float* w3 = (const float*)d_in[14];
    const float* b3 = (const float*)d_in[15];
    const float* g3 = (const float*)d_in[16];
    const float* be3 = (const float*)d_in[17];
    const float* w4 = (const float*)d_in[18];
    const float* b4 = (const float*)d_in[19];
    float* out = (float*)d_out;

    const int grid = 16384 / TS;  // 512 blocks
    wd_kernel<<<grid, NT, 0, stream>>>(
        user_ids, item_ids, wide_w, wide_b, user_table, item_table,
        w1, b1, g1, be1, w2, b2, g2, be2, w3, b3, g3, be3, w4, b4, out);
}

// Round 4
// 307.697 us; speedup vs baseline: 1.0214x; 1.0104x over previous
//
#include <hip/hip_runtime.h>

// WideAndDeep fused inference, fp32. Round 4: occupancy + prefetch.
// TS=16 samples/block, NT=256 threads (4 waves), 1024 blocks -> ~5 blocks/CU
// (~20 waves/CU vs ~12 in R3). Weight K-loop has explicit 1-deep register
// prefetch so the L2/L3 load latency (~300-600cyc; W1/W2 don't fit 32KB L1)
// overlaps the FMA stream across iteration boundaries.
// LDS ~25KB: xs[16][132] (reused as h2) + h1[16][260] (reused as h3).

#define NT 256
#define TS 16

constexpr int NUM_USERS = 500000;
// 1/sqrt(1 + 1e-5): eval-mode BN with running_mean=0, running_var=1
constexpr float BN_INV = 0.9999950000374997f;

struct __align__(16) Smem {
    float xs[TS * 132];   // input x (stride 132); reused as h2 (stride 132)
    float h1[TS * 260];   // h1 (stride 260); reused as h3 (stride 68)
};

#define FMA4(xk, wv, a)                      \
    do {                                     \
        (a).x = fmaf((xk), (wv).x, (a).x);   \
        (a).y = fmaf((xk), (wv).y, (a).y);   \
        (a).z = fmaf((xk), (wv).z, (a).z);   \
        (a).w = fmaf((xk), (wv).w, (a).w);   \
    } while (0)

// Linear(K,N)+ReLU+BN(eval) over the 16-sample tile, 4 waves per block.
// Wave w owns feature slice [w*FS, (w+1)*FS); FS = N/4. Lane: jg = lane%JG
// (4 features), sg = lane/JG (SPL samples). Weights read from global with
// 1-deep software prefetch; activations from LDS (padded strides).
template <int K, int KS, int N, int NS>
__device__ __forceinline__ void mlp_layer(
    const float* __restrict__ w, const float* __restrict__ bias,
    const float* __restrict__ gamma, const float* __restrict__ beta,
    const float* in_lds, float* out_lds, int t)
{
    constexpr int FS  = N / 4;        // features per wave
    constexpr int JG  = FS / 4;       // feature groups (of 4) per wave
    constexpr int SG  = 64 / JG;      // sample groups per wave
    constexpr int SPL = TS / SG;      // samples per lane
    constexpr int NW4 = N / 4;        // weight row stride in float4
    static_assert(SPL * SG == TS, "layout");

    const int wave = t >> 6, lane = t & 63;
    const int jg = lane % JG, sg = lane / JG;
    const int j0 = wave * FS + jg * 4;
    const int s0 = sg * SPL;

    float4 acc[SPL];
#pragma unroll
    for (int s = 0; s < SPL; ++s) acc[s] = make_float4(0.f, 0.f, 0.f, 0.f);

    const float4* wp = (const float4*)w + (j0 >> 2);

    // prefetch k4=0
    float4 wv0 = wp[0 * NW4];
    float4 wv1 = wp[1 * NW4];
    float4 wv2 = wp[2 * NW4];
    float4 wv3 = wp[3 * NW4];

#pragma unroll 2
    for (int k4 = 0; k4 < K; k4 += 4) {
        // issue next iteration's weight loads before consuming current ones
        float4 wn0, wn1, wn2, wn3;
        if (k4 + 4 < K) {
            wn0 = wp[(k4 + 4) * NW4];
            wn1 = wp[(k4 + 5) * NW4];
            wn2 = wp[(k4 + 6) * NW4];
            wn3 = wp[(k4 + 7) * NW4];
        }
        float4 xv[SPL];
#pragma unroll
        for (int s = 0; s < SPL; ++s)
            xv[s] = *(const float4*)&in_lds[(s0 + s) * KS + k4];
#pragma unroll
        for (int s = 0; s < SPL; ++s) {
            FMA4(xv[s].x, wv0, acc[s]);
            FMA4(xv[s].y, wv1, acc[s]);
            FMA4(xv[s].z, wv2, acc[s]);
            FMA4(xv[s].w, wv3, acc[s]);
        }
        wv0 = wn0; wv1 = wn1; wv2 = wn2; wv3 = wn3;
    }

    const float4 bv = *(const float4*)&bias[j0];
    const float4 gv = *(const float4*)&gamma[j0];
    const float4 ev = *(const float4*)&beta[j0];
#pragma unroll
    for (int s = 0; s < SPL; ++s) {
        float4 o;
        o.x = fmaxf(acc[s].x + bv.x, 0.f) * (gv.x * BN_INV) + ev.x;
        o.y = fmaxf(acc[s].y + bv.y, 0.f) * (gv.y * BN_INV) + ev.y;
        o.z = fmaxf(acc[s].z + bv.z, 0.f) * (gv.z * BN_INV) + ev.z;
        o.w = fmaxf(acc[s].w + bv.w, 0.f) * (gv.w * BN_INV) + ev.w;
        *(float4*)&out_lds[(s0 + s) * NS + j0] = o;
    }
}

__global__ __launch_bounds__(NT, 5) void wd_kernel(
    const int* __restrict__ user_ids, const int* __restrict__ item_ids,
    const float* __restrict__ wide_w, const float* __restrict__ wide_b,
    const float* __restrict__ user_table, const float* __restrict__ item_table,
    const float* __restrict__ w1, const float* __restrict__ b1,
    const float* __restrict__ g1, const float* __restrict__ be1,
    const float* __restrict__ w2, const float* __restrict__ b2,
    const float* __restrict__ g2, const float* __restrict__ be2,
    const float* __restrict__ w3, const float* __restrict__ b3,
    const float* __restrict__ g3, const float* __restrict__ be3,
    const float* __restrict__ w4, const float* __restrict__ b4,
    float* __restrict__ out)
{
    __shared__ Smem sm;
    const int t = threadIdx.x;
    const int sbase = blockIdx.x * TS;

    // ---- gather: xs[s][0:64] = user row, xs[s][64:128] = item row ----
    {
        const int s = t >> 4;         // 0..15
        const int p = t & 15;         // 0..15
        const int uid = user_ids[sbase + s];
        const int iid = item_ids[sbase + s];
        float4* row = (float4*)&sm.xs[s * 132];
        row[p]      = ((const float4*)(user_table + (long)uid * 64))[p];
        row[16 + p] = ((const float4*)(item_table + (long)iid * 64))[p];
    }

    // ---- wide path ----
    float widev = 0.0f;
    if (t < TS * 8 && (t & 7) == 0) {
        const int s = t >> 3;
        const int uid = user_ids[sbase + s];
        const int iid = item_ids[sbase + s];
        widev = wide_w[uid] + wide_w[NUM_USERS + iid] + wide_b[0];
    }
    __syncthreads();  // gather complete

    // ---- deep MLP ----
    mlp_layer<128, 132, 256, 260>(w1, b1, g1, be1, sm.xs, sm.h1, t);
    __syncthreads();
    mlp_layer<256, 260, 128, 132>(w2, b2, g2, be2, sm.h1, sm.xs, t);
    __syncthreads();
    mlp_layer<128, 132,  64,  68>(w3, b3, g3, be3, sm.xs, sm.h1, t);
    __syncthreads();

    // ---- layer 4: dot(h3[s], w4) + b4, 8 threads per sample ----
    if (t < TS * 8) {
        const int s = t >> 3;
        const int g = t & 7;
        const float* h = &sm.h1[s * 68 + g * 8];
        const float4 ha = *(const float4*)(h);
        const float4 hb = *(const float4*)(h + 4);
        const float4 wa = *(const float4*)(w4 + g * 8);
        const float4 wb = *(const float4*)(w4 + g * 8 + 4);
        float p = ha.x * wa.x + ha.y * wa.y + ha.z * wa.z + ha.w * wa.w
                + hb.x * wb.x + hb.y * wb.y + hb.z * wb.z + hb.w * wb.w;
        p += __shfl_down(p, 4);
        p += __shfl_down(p, 2);
        p += __shfl_down(p, 1);
        if (g == 0) out[sbase + s] = widev + p + b4[0];
    }
}

extern "C" void kernel_launch(void* const* d_in, const int* in_sizes, int n_in,
                              void* d_out, int out_size, void* d_ws, size_t ws_size,
                              hipStream_t stream) {
    (void)in_sizes; (void)n_in; (void)d_ws; (void)ws_size;
    const int*   user_ids   = (const int*)d_in[0];
    const int*   item_ids   = (const int*)d_in[1];
    const float* wide_w     = (const float*)d_in[2];
    const float* wide_b     = (const float*)d_in[3];
    const float* user_table = (const float*)d_in[4];
    const float* item_table = (const float*)d_in[5];
    const float* w1 = (const float*)d_in[6];
    const float* b1 = (const float*)d_in[7];
    const float* g1 = (const float*)d_in[8];
    const float* be1 = (const float*)d_in[9];
    const float* w2 = (const float*)d_in[10];
    const float* b2 = (const float*)d_in[11];
    const float* g2 = (const float*)d_in[12];
    const float* be2 = (const float*)d_in[13];
    const float* w3 = (const float*)d_in[14];
    const float* b3 = (const float*)d_in[15];
    const float* g3 = (const float*)d_in[16];
    const float* be3 = (const float*)d_in[17];
    const float* w4 = (const float*)d_in[18];
    const float* b4 = (const float*)d_in[19];
    float* out = (float*)d_out;

    const int grid = 16384 / TS;  // 1024 blocks
    wd_kernel<<<grid, NT, 0, stream>>>(
        user_ids, item_ids, wide_w, wide_b, user_table, item_table,
        w1, b1, g1, be1, w2, b2, g2, be2, w3, b3, g3, be3, w4, b4, out);
}

// Round 5
// 260.514 us; speedup vs baseline: 1.2064x; 1.1811x over previous
//
#include <hip/hip_runtime.h>

// WideAndDeep fused inference. Round 5: split-bf16 MFMA.
// prep kernel: W1..W3 fp32 -> (hi,lo) bf16 A-fragments in d_ws, packed in
//   [ktile][ftile][lane] order so the main kernel's A-frag load is ONE
//   coalesced 16B/lane dwordx4 (L2-resident, 288 KB total).
// main kernel: 32 samples/block, 256 thr (4 waves, waves split features).
//   Activations in LDS as bf16 hi/lo (stride K+8: 16B-aligned, <=2-way banks).
//   D = A(W^T frag) x B(x frag): mfma_f32_16x16x32_bf16, 3 products per tile
//   (hh, hl, lh) => ~1e-5 relative accuracy. Epilogue fuses bias+ReLU+BN.

#define NT 256
#define TS 32

constexpr int NUM_USERS = 500000;
constexpr float BN_INV = 0.9999950000374997f;  // 1/sqrt(1+1e-5)

typedef float f32x4 __attribute__((ext_vector_type(4)));
typedef short short8 __attribute__((ext_vector_type(8)));

union U4S8 { uint4 u; short8 s; };

__device__ __forceinline__ unsigned short f2bf(float x) {
    unsigned u = __float_as_uint(x);
    return (unsigned short)((u + 0x7fffu + ((u >> 16) & 1u)) >> 16);
}
__device__ __forceinline__ float bf2f(unsigned short h) {
    return __uint_as_float(((unsigned)h) << 16);
}

// split 4 floats into bf16 hi/lo and store as uint2 each (8B, aligned)
__device__ __forceinline__ void split_store4(unsigned short* ph, unsigned short* pl, float4 v) {
    unsigned short h0 = f2bf(v.x), h1 = f2bf(v.y), h2 = f2bf(v.z), h3 = f2bf(v.w);
    unsigned short l0 = f2bf(v.x - bf2f(h0)), l1 = f2bf(v.y - bf2f(h1));
    unsigned short l2 = f2bf(v.z - bf2f(h2)), l3 = f2bf(v.w - bf2f(h3));
    uint2 hw, lw;
    hw.x = (unsigned)h0 | ((unsigned)h1 << 16); hw.y = (unsigned)h2 | ((unsigned)h3 << 16);
    lw.x = (unsigned)l0 | ((unsigned)l1 << 16); lw.y = (unsigned)l2 | ((unsigned)l3 << 16);
    *(uint2*)ph = hw; *(uint2*)pl = lw;
}

// ---------- prep: build split-bf16 A-fragments for W1..W3 in d_ws ----------
// uint4 index map: L1 hi [0,4096) lo [4096,8192); L2 hi [8192,12288)
// lo [12288,16384); L3 hi [16384,17408) lo [17408,18432). 288 KB total.
__global__ __launch_bounds__(256) void wd_prep(
    const float* __restrict__ w1, const float* __restrict__ w2,
    const float* __restrict__ w3, uint4* __restrict__ ws)
{
    int tid = blockIdx.x * 256 + threadIdx.x;
    if (tid >= 9216) return;
    const float* W; int ncols, kt, fg, lane, hib, lob, idx;
    if (tid < 4096)      { W = w1; ncols = 256; int r = tid;        kt = r >> 10; fg = (r >> 6) & 15; lane = r & 63; hib = 0;     lob = 4096;  idx = r; }
    else if (tid < 8192) { W = w2; ncols = 128; int r = tid - 4096; kt = r >> 9;  fg = (r >> 6) & 7;  lane = r & 63; hib = 8192;  lob = 12288; idx = r; }
    else                 { W = w3; ncols = 64;  int r = tid - 8192; kt = r >> 8;  fg = (r >> 6) & 3;  lane = r & 63; hib = 16384; lob = 17408; idx = r; }
    const int q = lane >> 4, rr = lane & 15;
    const int k0 = kt * 32 + q * 8;      // 8 consecutive k
    const int n  = fg * 16 + rr;         // feature (A-row)
    unsigned short hs[8], ls[8];
#pragma unroll
    for (int j = 0; j < 8; ++j) {
        float v = W[(k0 + j) * ncols + n];
        unsigned short h = f2bf(v);
        hs[j] = h;
        ls[j] = f2bf(v - bf2f(h));
    }
    uint4 hu, lu;
    hu.x = (unsigned)hs[0] | ((unsigned)hs[1] << 16); hu.y = (unsigned)hs[2] | ((unsigned)hs[3] << 16);
    hu.z = (unsigned)hs[4] | ((unsigned)hs[5] << 16); hu.w = (unsigned)hs[6] | ((unsigned)hs[7] << 16);
    lu.x = (unsigned)ls[0] | ((unsigned)ls[1] << 16); lu.y = (unsigned)ls[2] | ((unsigned)ls[3] << 16);
    lu.z = (unsigned)ls[4] | ((unsigned)ls[5] << 16); lu.w = (unsigned)ls[6] | ((unsigned)ls[7] << 16);
    ws[hib + idx] = hu;
    ws[lob + idx] = lu;
}

// ---------- main ----------
struct __align__(16) Smem {
    unsigned short xh[TS * 136], xl[TS * 136];  // K=128 buffers (x, h2)
    unsigned short yh[TS * 264], yl[TS * 264];  // K=256 buffer (h1); h3 @ stride 72
};

// Linear(K,N)+ReLU+BN over 32-sample LDS tile via split-bf16 MFMA.
// Wave owns N/4 features (FT=N/64 16-wide ftiles); 2 sample-tiles of 16.
template <int K, int N, int SIN, int SOUT>
__device__ __forceinline__ void mfma_layer(
    const uint4* __restrict__ Ah, const uint4* __restrict__ Al,
    const float* __restrict__ bias, const float* __restrict__ gamma,
    const float* __restrict__ beta,
    const unsigned short* inh, const unsigned short* inl,
    unsigned short* outh, unsigned short* outl, int t)
{
    constexpr int KT = K / 32, FT = N / 64, FTOT = N / 16;
    const int wave = t >> 6, lane = t & 63, q = lane >> 4, r = lane & 15;

    f32x4 zero = {0.f, 0.f, 0.f, 0.f};
    f32x4 acc[FT][2];
#pragma unroll
    for (int ft = 0; ft < FT; ++ft)
#pragma unroll
        for (int s = 0; s < 2; ++s) acc[ft][s] = zero;

#pragma unroll
    for (int kt = 0; kt < KT; ++kt) {
        short8 bh[2], bl[2];
#pragma unroll
        for (int s = 0; s < 2; ++s) {
            const int bi = (s * 16 + r) * SIN + kt * 32 + q * 8;
            bh[s] = *(const short8*)&inh[bi];   // B frag: sample=lane&15, k-strip
            bl[s] = *(const short8*)&inl[bi];
        }
#pragma unroll
        for (int ft = 0; ft < FT; ++ft) {
            const int fo = (kt * FTOT + wave * FT + ft) * 64 + lane;
            U4S8 ah, al; ah.u = Ah[fo]; al.u = Al[fo];   // coalesced 16B/lane
#pragma unroll
            for (int s = 0; s < 2; ++s) {
                acc[ft][s] = __builtin_amdgcn_mfma_f32_16x16x32_bf16(ah.s, bh[s], acc[ft][s], 0, 0, 0);
                acc[ft][s] = __builtin_amdgcn_mfma_f32_16x16x32_bf16(ah.s, bl[s], acc[ft][s], 0, 0, 0);
                acc[ft][s] = __builtin_amdgcn_mfma_f32_16x16x32_bf16(al.s, bh[s], acc[ft][s], 0, 0, 0);
            }
        }
    }

    // epilogue: D row=(q*4+reg)=feature, col=lane&15=sample (m89 layout)
#pragma unroll
    for (int ft = 0; ft < FT; ++ft) {
        const int f = (wave * FT + ft) * 16 + q * 4;
        const float4 bv = *(const float4*)&bias[f];
        const float4 gv = *(const float4*)&gamma[f];
        const float4 ev = *(const float4*)&beta[f];
#pragma unroll
        for (int s = 0; s < 2; ++s) {
            const int sample = s * 16 + r;
            float4 o;
            o.x = fmaxf(acc[ft][s][0] + bv.x, 0.f) * (gv.x * BN_INV) + ev.x;
            o.y = fmaxf(acc[ft][s][1] + bv.y, 0.f) * (gv.y * BN_INV) + ev.y;
            o.z = fmaxf(acc[ft][s][2] + bv.z, 0.f) * (gv.z * BN_INV) + ev.z;
            o.w = fmaxf(acc[ft][s][3] + bv.w, 0.f) * (gv.w * BN_INV) + ev.w;
            split_store4(&outh[sample * SOUT + f], &outl[sample * SOUT + f], o);
        }
    }
}

__global__ __launch_bounds__(NT) void wd_main(
    const int* __restrict__ user_ids, const int* __restrict__ item_ids,
    const float* __restrict__ wide_w, const float* __restrict__ wide_b,
    const float* __restrict__ user_table, const float* __restrict__ item_table,
    const float* __restrict__ b1, const float* __restrict__ g1, const float* __restrict__ be1,
    const float* __restrict__ b2, const float* __restrict__ g2, const float* __restrict__ be2,
    const float* __restrict__ b3, const float* __restrict__ g3, const float* __restrict__ be3,
    const float* __restrict__ w4, const float* __restrict__ b4,
    const uint4* __restrict__ wsA, float* __restrict__ out)
{
    __shared__ Smem sm;
    const int t = threadIdx.x;
    const int sbase = blockIdx.x * TS;
    const int s = t >> 3, g = t & 7;   // 8 threads per sample

    // ---- gather + split to bf16 hi/lo in LDS ----
    {
        const int uid = user_ids[sbase + s];
        const int iid = item_ids[sbase + s];
        const float* src = (g < 4) ? user_table + (long)uid * 64 + g * 16
                                   : item_table + (long)iid * 64 + (g - 4) * 16;
#pragma unroll
        for (int j = 0; j < 4; ++j) {
            float4 v = ((const float4*)src)[j];
            const int di = s * 136 + g * 16 + j * 4;
            split_store4(&sm.xh[di], &sm.xl[di], v);
        }
    }
    // ---- wide path (thread that writes out[s]) ----
    float widev = 0.f;
    if (g == 0)
        widev = wide_w[user_ids[sbase + s]] + wide_w[NUM_USERS + item_ids[sbase + s]] + wide_b[0];
    __syncthreads();

    mfma_layer<128, 256, 136, 264>(wsA,         wsA + 4096,  b1, g1, be1, sm.xh, sm.xl, sm.yh, sm.yl, t);
    __syncthreads();
    mfma_layer<256, 128, 264, 136>(wsA + 8192,  wsA + 12288, b2, g2, be2, sm.yh, sm.yl, sm.xh, sm.xl, t);
    __syncthreads();
    mfma_layer<128, 64, 136, 72>(wsA + 16384, wsA + 17408, b3, g3, be3, sm.xh, sm.xl, sm.yh, sm.yl, t);
    __syncthreads();

    // ---- layer 4: dot(h3[s], w4), 8 threads/sample, shuffle-reduce ----
    {
        const short8 hh = *(const short8*)&sm.yh[s * 72 + g * 8];
        const short8 hl = *(const short8*)&sm.yl[s * 72 + g * 8];
        const float4 wa = *(const float4*)(w4 + g * 8);
        const float4 wb = *(const float4*)(w4 + g * 8 + 4);
        float h0 = bf2f((unsigned short)hh[0]) + bf2f((unsigned short)hl[0]);
        float h1 = bf2f((unsigned short)hh[1]) + bf2f((unsigned short)hl[1]);
        float h2 = bf2f((unsigned short)hh[2]) + bf2f((unsigned short)hl[2]);
        float h3 = bf2f((unsigned short)hh[3]) + bf2f((unsigned short)hl[3]);
        float h4 = bf2f((unsigned short)hh[4]) + bf2f((unsigned short)hl[4]);
        float h5 = bf2f((unsigned short)hh[5]) + bf2f((unsigned short)hl[5]);
        float h6 = bf2f((unsigned short)hh[6]) + bf2f((unsigned short)hl[6]);
        float h7 = bf2f((unsigned short)hh[7]) + bf2f((unsigned short)hl[7]);
        float p = h0 * wa.x + h1 * wa.y + h2 * wa.z + h3 * wa.w
                + h4 * wb.x + h5 * wb.y + h6 * wb.z + h7 * wb.w;
        p += __shfl_down(p, 4);
        p += __shfl_down(p, 2);
        p += __shfl_down(p, 1);
        if (g == 0) out[sbase + s] = widev + p + b4[0];
    }
}

extern "C" void kernel_launch(void* const* d_in, const int* in_sizes, int n_in,
                              void* d_out, int out_size, void* d_ws, size_t ws_size,
                              hipStream_t stream) {
    (void)in_sizes; (void)n_in; (void)ws_size;
    const int*   user_ids   = (const int*)d_in[0];
    const int*   item_ids   = (const int*)d_in[1];
    const float* wide_w     = (const float*)d_in[2];
    const float* wide_b     = (const float*)d_in[3];
    const float* user_table = (const float*)d_in[4];
    const float* item_table = (const float*)d_in[5];
    const float* w1 = (const float*)d_in[6];
    const float* b1 = (const float*)d_in[7];
    const float* g1 = (const float*)d_in[8];
    const float* be1 = (const float*)d_in[9];
    const float* w2 = (const float*)d_in[10];
    const float* b2 = (const float*)d_in[11];
    const float* g2 = (const float*)d_in[12];
    const float* be2 = (const float*)d_in[13];
    const float* w3 = (const float*)d_in[14];
    const float* b3 = (const float*)d_in[15];
    const float* g3 = (const float*)d_in[16];
    const float* be3 = (const float*)d_in[17];
    const float* w4 = (const float*)d_in[18];
    const float* b4 = (const float*)d_in[19];
    float* out = (float*)d_out;
    uint4* ws = (uint4*)d_ws;   // needs 288 KB

    wd_prep<<<36, 256, 0, stream>>>(w1, w2, w3, ws);
    wd_main<<<16384 / TS, NT, 0, stream>>>(
        user_ids, item_ids, wide_w, wide_b, user_table, item_table,
        b1, g1, be1, b2, g2, be2, b3, g3, be3, w4, b4,
        (const uint4*)ws, out);
}